// Round 1
// baseline (648.055 us; speedup 1.0000x reference)
//
#include <hip/hip_runtime.h>
#include <hip/hip_bf16.h>
#include <stdint.h>

// GINE edge layer on MI355X:
//   de = concat([e, x[src], x[dst]]) @ W1 + b1 ; de = silu(de); h = e + de
//   out = GraphNorm(h, seg=batch[src])  (per-graph mean/var, ms-scaled mean)
// Decomposition: concat@W1 = e@W1a + xb[src] + xc[dst], xb/xc precomputed per NODE.
// GraphNorm one-pass: var = E[h^2] - m^2*ms*(2-ms); out = A[g,d]*h + C[g,d].

typedef float   f32x4 __attribute__((ext_vector_type(4)));
typedef short   s16x8 __attribute__((ext_vector_type(8)));
typedef uint32_t u32x4 __attribute__((ext_vector_type(4)));

#define NGRAPH 64

__device__ __forceinline__ void gld16(const void* g, void* l) {
  __builtin_amdgcn_global_load_lds(
      (const __attribute__((address_space(1))) uint32_t*)g,
      (__attribute__((address_space(3))) uint32_t*)l, 16, 0, 0);
}

__device__ __forceinline__ short f2bf(float f) {
  __bf16 b = (__bf16)f;                       // RTNE; compiler fuses to v_cvt_pk_bf16_f32
  return __builtin_bit_cast(short, b);
}
__device__ __forceinline__ float bf2f(uint32_t u) {
  return __uint_as_float((u & 0xffffu) << 16);
}

// permuted d-index for the LDS/global sum tables: d = c*8+j -> dp = c | (j<<5)
// (spreads the 8 per-thread columns across all 32 banks for ds_add_f32)
__device__ __forceinline__ int dperm(int d) { return (d >> 3) | ((d & 7) << 5); }

// ---------------------------------------------------------------- zero tables
__global__ __launch_bounds__(256) void k_zero(float* p, int n) {
  int i = blockIdx.x * 256 + threadIdx.x;
  if (i < n) p[i] = 0.f;
}

// ------------------------------------------- W1 f32 [768][256] -> transposed bf16
// wta [n=256][k=256]  = W1[k][n]            (k in [0,256))
// wtbc[j=512][k=256]: j<256 -> W1[256+k][j] ; j>=256 -> W1[512+k][j-256]
__global__ __launch_bounds__(256) void k_wconv(const float* __restrict__ W1,
                                               uint16_t* __restrict__ wta,
                                               uint16_t* __restrict__ wtbc) {
  int k = blockIdx.x;            // 0..767
  int n = threadIdx.x;           // 0..255
  uint16_t v = (uint16_t)f2bf(W1[k * 256 + n]);
  if (k < 256)      wta[n * 256 + k] = v;
  else if (k < 512) wtbc[n * 256 + (k - 256)] = v;
  else              wtbc[(n + 256) * 256 + (k - 512)] = v;
}

// ------------------------------------------------- node GEMM: xbc = x @ Wbc
// BM=32, BN=512, BK=64; 4 waves = 1x4 (wave w owns cols w*128..+128)
__global__ __launch_bounds__(256, 2) void k_nodegemm(const float* __restrict__ x,
                                                     const uint16_t* __restrict__ wtbc,
                                                     float* __restrict__ xbc, int NV) {
  __shared__ float    xt[32 * 64];        // 8 KB, f32, 16B slots XOR-swizzled by (row&15)
  __shared__ uint16_t wtb[512 * 64];      // 64 KB, bf16, slots XOR-swizzled by (n&7)
  const int tid = threadIdx.x, wave = tid >> 6, lane = tid & 63;
  const int m0 = blockIdx.x * 32;
  const int cl = lane & 15, rq = lane >> 4;

  f32x4 acc[2][8];
#pragma unroll
  for (int a = 0; a < 2; ++a)
#pragma unroll
    for (int b = 0; b < 8; ++b) acc[a][b] = (f32x4)0.f;

  for (int kk = 0; kk < 4; ++kk) {
    const int k0 = kk * 64;
    // stage x tile [32][64] f32 (8 insts; source XOR-pre-swizzled, LDS linear)
#pragma unroll
    for (int ii = 0; ii < 2; ++ii) {
      int i = wave * 2 + ii;
      int row = i * 4 + rq;
      int k8 = cl ^ (row & 15);
      int grow = m0 + row; if (grow > NV - 1) grow = NV - 1;
      gld16((const char*)x + ((size_t)grow * 256 + k0) * 4 + k8 * 16,
            (char*)xt + i * 1024);
    }
    // stage Wbc^T chunk [512][64] bf16 (64 insts)
#pragma unroll
    for (int ii = 0; ii < 16; ++ii) {
      int i = wave * 16 + ii;
      int n = i * 8 + (lane >> 3);
      int k8 = (lane & 7) ^ (n & 7);
      gld16((const char*)wtbc + ((size_t)n * 256 + k0) * 2 + k8 * 16,
            (char*)wtb + i * 1024);
    }
    __syncthreads();
#pragma unroll
    for (int ks = 0; ks < 2; ++ks) {
      s16x8 a[2], b[8];
#pragma unroll
      for (int mt = 0; mt < 2; ++mt) {
        int row = mt * 16 + cl;
        int sbase = ks * 8 + rq * 2;
        int sw = (row & 15) << 4;
        f32x4 f0 = *(const f32x4*)((const char*)xt + row * 256 + (((sbase    ) << 4) ^ sw));
        f32x4 f1 = *(const f32x4*)((const char*)xt + row * 256 + (((sbase + 1) << 4) ^ sw));
        s16x8 t;
        t[0] = f2bf(f0[0]); t[1] = f2bf(f0[1]); t[2] = f2bf(f0[2]); t[3] = f2bf(f0[3]);
        t[4] = f2bf(f1[0]); t[5] = f2bf(f1[1]); t[6] = f2bf(f1[2]); t[7] = f2bf(f1[3]);
        a[mt] = t;
      }
#pragma unroll
      for (int nt = 0; nt < 8; ++nt) {
        int n = wave * 128 + nt * 16 + cl;
        int byt = n * 128 + ((((ks * 4 + rq)) << 4) ^ ((n & 7) << 4));
        b[nt] = *(const s16x8*)((const char*)wtb + byt);
      }
#pragma unroll
      for (int mt = 0; mt < 2; ++mt)
#pragma unroll
        for (int nt = 0; nt < 8; ++nt)
          acc[mt][nt] = __builtin_amdgcn_mfma_f32_16x16x32_bf16(a[mt], b[nt], acc[mt][nt], 0, 0, 0);
    }
    __syncthreads();
  }
#pragma unroll
  for (int mt = 0; mt < 2; ++mt)
#pragma unroll
    for (int q = 0; q < 4; ++q) {
      int row = m0 + mt * 16 + rq * 4 + q;
      if (row < NV) {
#pragma unroll
        for (int nt = 0; nt < 8; ++nt) {
          int col = wave * 128 + nt * 16 + cl;
          xbc[(size_t)row * 512 + col] = acc[mt][nt][q];
        }
      }
    }
}

// ------------------------------------------------- edge GEMM + epilogue
// BM=128, BN=256, BK=64; waves 2x2 (wr rows 64, wc cols 128)
template <bool BF16H>
__global__ __launch_bounds__(256, 2) void k_edgegemm(
    const float* __restrict__ e, const uint16_t* __restrict__ wta,
    const float* __restrict__ xbc, const float* __restrict__ b1,
    const int* __restrict__ srcI, const int* __restrict__ dstI,
    const int* __restrict__ batch, void* __restrict__ hout,
    int* __restrict__ seg, int E) {
  __shared__ float    et[128 * 64];       // 32 KB
  __shared__ uint16_t wt[256 * 64];       // 32 KB
  const int tid = threadIdx.x, wave = tid >> 6, lane = tid & 63;
  const int wr = wave >> 1, wc = wave & 1;
  const int m0 = blockIdx.x * 128;
  const int cl = lane & 15, rq = lane >> 4;

  f32x4 acc[4][8];
#pragma unroll
  for (int a = 0; a < 4; ++a)
#pragma unroll
    for (int b = 0; b < 8; ++b) acc[a][b] = (f32x4)0.f;

  for (int kk = 0; kk < 4; ++kk) {
    const int k0 = kk * 64;
#pragma unroll
    for (int ii = 0; ii < 8; ++ii) {      // e tile [128][64] f32
      int i = wave * 8 + ii;
      int row = i * 4 + rq;
      int k8 = cl ^ (row & 15);
      int grow = m0 + row; if (grow > E - 1) grow = E - 1;
      gld16((const char*)e + ((size_t)grow * 256 + k0) * 4 + k8 * 16,
            (char*)et + i * 1024);
    }
#pragma unroll
    for (int ii = 0; ii < 8; ++ii) {      // W1a^T chunk [256][64] bf16
      int i = wave * 8 + ii;
      int n = i * 8 + (lane >> 3);
      int k8 = (lane & 7) ^ (n & 7);
      gld16((const char*)wta + ((size_t)n * 256 + k0) * 2 + k8 * 16,
            (char*)wt + i * 1024);
    }
    __syncthreads();
#pragma unroll
    for (int ks = 0; ks < 2; ++ks) {
      s16x8 a[4], b[8];
#pragma unroll
      for (int mt = 0; mt < 4; ++mt) {
        int row = wr * 64 + mt * 16 + cl;
        int sbase = ks * 8 + rq * 2;
        int sw = (row & 15) << 4;
        f32x4 f0 = *(const f32x4*)((const char*)et + row * 256 + (((sbase    ) << 4) ^ sw));
        f32x4 f1 = *(const f32x4*)((const char*)et + row * 256 + (((sbase + 1) << 4) ^ sw));
        s16x8 t;
        t[0] = f2bf(f0[0]); t[1] = f2bf(f0[1]); t[2] = f2bf(f0[2]); t[3] = f2bf(f0[3]);
        t[4] = f2bf(f1[0]); t[5] = f2bf(f1[1]); t[6] = f2bf(f1[2]); t[7] = f2bf(f1[3]);
        a[mt] = t;
      }
#pragma unroll
      for (int nt = 0; nt < 8; ++nt) {
        int n = wc * 128 + nt * 16 + cl;
        int byt = n * 128 + ((((ks * 4 + rq)) << 4) ^ ((n & 7) << 4));
        b[nt] = *(const s16x8*)((const char*)wt + byt);
      }
#pragma unroll
      for (int mt = 0; mt < 4; ++mt)
#pragma unroll
        for (int nt = 0; nt < 8; ++nt)
          acc[mt][nt] = __builtin_amdgcn_mfma_f32_16x16x32_bf16(a[mt], b[nt], acc[mt][nt], 0, 0, 0);
    }
    __syncthreads();
  }

  // epilogue: de = acc + xb[src] + xc[dst] + b1 ; h = e + silu(de)
  float b1v[8];
#pragma unroll
  for (int nt = 0; nt < 8; ++nt) b1v[nt] = b1[wc * 128 + nt * 16 + cl];

#pragma unroll
  for (int mt = 0; mt < 4; ++mt) {
#pragma unroll
    for (int q = 0; q < 4; ++q) {
      int row = m0 + wr * 64 + mt * 16 + rq * 4 + q;
      bool valid = row < E;
      int rcl = valid ? row : E - 1;
      int s = srcI[rcl], dd = dstI[rcl];
      if (valid && wc == 0 && cl == 0) seg[row] = batch[s];
#pragma unroll
      for (int nt = 0; nt < 8; ++nt) {
        int col = wc * 128 + nt * 16 + cl;
        float de = acc[mt][nt][q] + xbc[(size_t)s * 512 + col]
                 + xbc[(size_t)dd * 512 + 256 + col] + b1v[nt];
        float sig = 1.f / (1.f + __expf(-de));
        float h = e[(size_t)rcl * 256 + col] + de * sig;
        if (valid) {
          if (BF16H) ((uint16_t*)hout)[(size_t)row * 256 + col] = (uint16_t)f2bf(h);
          else       ((float*)hout)[(size_t)row * 256 + col] = h;
        }
      }
    }
  }
}

// ------------------------------------------------- segment sums over h
template <bool BF16H>
__global__ __launch_bounds__(512, 1) void k_sums(const void* __restrict__ h,
                                                 const int* __restrict__ seg,
                                                 float* __restrict__ gsum,
                                                 float* __restrict__ gsq,
                                                 float* __restrict__ gcnt, int E) {
  __shared__ float ls[NGRAPH * 256];      // 64 KB (d-permuted layout)
  __shared__ float lq[NGRAPH * 256];      // 64 KB
  __shared__ float lc[NGRAPH];
  const int t = threadIdx.x;
  for (int i = t; i < NGRAPH * 256; i += 512) { ls[i] = 0.f; lq[i] = 0.f; }
  if (t < NGRAPH) lc[t] = 0.f;
  __syncthreads();
  const int ro = t >> 5, c = t & 31;
  const int step = gridDim.x * 16;
  for (int r0 = blockIdx.x * 16; r0 < E; r0 += step) {
    int r = r0 + ro;
    if (r < E) {
      int g = seg[r];
      float v[8];
      if (BF16H) {
        u32x4 p = *(const u32x4*)((const uint16_t*)h + (size_t)r * 256 + c * 8);
#pragma unroll
        for (int j = 0; j < 4; ++j) { v[2*j] = bf2f(p[j]); v[2*j+1] = bf2f(p[j] >> 16); }
      } else {
        const float* hp = (const float*)h + (size_t)r * 256 + c * 8;
#pragma unroll
        for (int j = 0; j < 8; ++j) v[j] = hp[j];
      }
      if (c == 0) atomicAdd(&lc[g], 1.f);
#pragma unroll
      for (int j = 0; j < 8; ++j) {
        int dp = c | (j << 5);            // dperm(c*8+j): conflict-free across lanes
        atomicAdd(&ls[g * 256 + dp], v[j]);
        atomicAdd(&lq[g * 256 + dp], v[j] * v[j]);
      }
    }
  }
  __syncthreads();
  for (int i = t; i < NGRAPH * 256; i += 512) {
    unsafeAtomicAdd(&gsum[i], ls[i]);
    unsafeAtomicAdd(&gsq[i], lq[i]);
  }
  if (t < NGRAPH) unsafeAtomicAdd(&gcnt[t], lc[t]);
}

// ------------------------------------------------- per-(g,d) affine tables
__global__ __launch_bounds__(256) void k_stats(const float* __restrict__ gsum,
                                               const float* __restrict__ gsq,
                                               const float* __restrict__ gcnt,
                                               const float* __restrict__ w,
                                               const float* __restrict__ b,
                                               const float* __restrict__ ms,
                                               float* __restrict__ atab,
                                               float* __restrict__ ctab) {
  int g = blockIdx.x, d = threadIdx.x;
  int dp = dperm(d);
  float cnt = fmaxf(gcnt[g], 1.f);
  float m   = gsum[g * 256 + dp] / cnt;
  float msq = gsq[g * 256 + dp] / cnt;
  float sc  = ms[d];
  float var = msq - m * m * sc * (2.f - sc);
  float rstd = rsqrtf(fmaxf(var, 0.f) + 1e-5f);
  float A = w[d] * rstd;
  atab[g * 256 + d] = A;
  ctab[g * 256 + d] = b[d] - A * sc * m;
}

// ------------------------------------------------- apply: out = A[g]*h + C[g]
template <bool BF16H>
__global__ __launch_bounds__(256) void k_apply(const void* __restrict__ h,
                                               const int* __restrict__ seg,
                                               const float* __restrict__ atab,
                                               const float* __restrict__ ctab,
                                               float* __restrict__ out, int E) {
  const long long total = (long long)E * 32;
  for (long long i = (long long)blockIdx.x * 256 + threadIdx.x; i < total;
       i += (long long)gridDim.x * 256) {
    int row = (int)(i >> 5);
    int c8 = ((int)i & 31) * 8;
    int g = seg[row];
    const f32x4* Ap = (const f32x4*)(atab + g * 256 + c8);
    const f32x4* Cp = (const f32x4*)(ctab + g * 256 + c8);
    f32x4 A0 = Ap[0], A1 = Ap[1], C0 = Cp[0], C1 = Cp[1];
    f32x4 h0, h1;
    if (BF16H) {
      u32x4 p = *(const u32x4*)((const uint16_t*)h + (size_t)row * 256 + c8);
      h0[0] = bf2f(p[0]); h0[1] = bf2f(p[0] >> 16);
      h0[2] = bf2f(p[1]); h0[3] = bf2f(p[1] >> 16);
      h1[0] = bf2f(p[2]); h1[1] = bf2f(p[2] >> 16);
      h1[2] = bf2f(p[3]); h1[3] = bf2f(p[3] >> 16);
    } else {
      const f32x4* hp = (const f32x4*)((const float*)h + (size_t)row * 256 + c8);
      h0 = hp[0]; h1 = hp[1];
    }
    f32x4 o0 = A0 * h0 + C0, o1 = A1 * h1 + C1;
    f32x4* op = (f32x4*)(out + (size_t)row * 256 + c8);
    op[0] = o0; op[1] = o1;
  }
}

// ----------------------------------------------------------------- launch
extern "C" void kernel_launch(void* const* d_in, const int* in_sizes, int n_in,
                              void* d_out, int out_size, void* d_ws, size_t ws_size,
                              hipStream_t stream) {
  const float* x     = (const float*)d_in[0];
  const float* e     = (const float*)d_in[1];
  const int*   batch = (const int*)d_in[2];
  const int*   eidx  = (const int*)d_in[3];
  const float* W1    = (const float*)d_in[4];
  const float* b1    = (const float*)d_in[5];
  const float* gw    = (const float*)d_in[6];
  const float* gb    = (const float*)d_in[7];
  const float* gms   = (const float*)d_in[8];
  const int NV = in_sizes[0] / 256;
  const int E  = in_sizes[1] / 256;
  const int* srcI = eidx;
  const int* dstI = eidx + E;

  char* ws = (char*)d_ws;
  size_t off = 0;
  auto alloc = [&](size_t bytes) {
    size_t o = off;
    off += (bytes + 255) & ~(size_t)255;
    return o;
  };
  size_t o_wta  = alloc(256 * 256 * 2);
  size_t o_wtbc = alloc(512 * 256 * 2);
  size_t o_gsum = alloc(NGRAPH * 256 * 4);
  size_t o_gsq  = alloc(NGRAPH * 256 * 4);
  size_t o_gcnt = alloc(256);
  size_t o_atab = alloc(NGRAPH * 256 * 4);
  size_t o_ctab = alloc(NGRAPH * 256 * 4);
  size_t o_seg  = alloc((size_t)E * 4);
  size_t o_xbc  = alloc((size_t)NV * 512 * 4);
  size_t o_h    = alloc((size_t)E * 256 * 2);
  const bool fast = ws_size >= off;   // h (bf16) fits in ws? else stage f32 in d_out

  uint16_t* wta  = (uint16_t*)(ws + o_wta);
  uint16_t* wtbc = (uint16_t*)(ws + o_wtbc);
  float* gsum = (float*)(ws + o_gsum);
  float* gsq  = (float*)(ws + o_gsq);
  float* gcnt = (float*)(ws + o_gcnt);
  float* atab = (float*)(ws + o_atab);
  float* ctab = (float*)(ws + o_ctab);
  int*   seg  = (int*)(ws + o_seg);
  float* xbc  = (float*)(ws + o_xbc);
  void*  hbuf = fast ? (void*)(ws + o_h) : d_out;

  const int nz = NGRAPH * 256 * 2 + 64;   // gsum|gsq|gcnt contiguous
  k_zero<<<(nz + 255) / 256, 256, 0, stream>>>(gsum, nz);
  k_wconv<<<768, 256, 0, stream>>>(W1, wta, wtbc);
  k_nodegemm<<<(NV + 31) / 32, 256, 0, stream>>>(x, wtbc, xbc, NV);
  if (fast) {
    k_edgegemm<true><<<(E + 127) / 128, 256, 0, stream>>>(e, wta, xbc, b1, srcI, dstI,
                                                          batch, hbuf, seg, E);
    k_sums<true><<<256, 512, 0, stream>>>(hbuf, seg, gsum, gsq, gcnt, E);
  } else {
    k_edgegemm<false><<<(E + 127) / 128, 256, 0, stream>>>(e, wta, xbc, b1, srcI, dstI,
                                                           batch, hbuf, seg, E);
    k_sums<false><<<256, 512, 0, stream>>>(hbuf, seg, gsum, gsq, gcnt, E);
  }
  k_stats<<<NGRAPH, 256, 0, stream>>>(gsum, gsq, gcnt, gw, gb, gms, atab, ctab);
  if (fast)
    k_apply<true><<<2048, 256, 0, stream>>>(hbuf, seg, atab, ctab, (float*)d_out, E);
  else
    k_apply<false><<<2048, 256, 0, stream>>>(hbuf, seg, atab, ctab, (float*)d_out, E);
}